// Round 1
// baseline (162.206 us; speedup 1.0000x reference)
//
#include <hip/hip_runtime.h>
#include <hip/hip_bf16.h>

typedef __attribute__((ext_vector_type(8))) short short8;
typedef __attribute__((ext_vector_type(4))) float float4v;

// Workspace layout (bytes):
//   xT   bf16 [16][34][34][256]                      : 9,469,952
//   Wg   bf16 [9][8][2][4][128][8]  (s,chunk,nt,quad,n,c8) : 1,179,648
//   biasout f32 [256]                                : 1,024
#define XT_ELEMS (16*34*34*256)
#define WG_ELEMS (9*8*2*4*128*8)
#define XT_BYTES (XT_ELEMS*2)
#define WG_BYTES (WG_ELEMS*2)

// ---------------------------------------------------------------------------
// Kernel 0: x f32 [16][256][32][32] -> xT bf16 [16][34][34][256] (interior).
// Pad ring is zeroed by hipMemsetAsync before this kernel.
// LDS 32x33 transpose tile: coalesced f32 reads along w, coalesced bf16
// writes along c.
// ---------------------------------------------------------------------------
__global__ __launch_bounds__(256) void k_transpose(const float* __restrict__ x,
                                                   __hip_bfloat16* __restrict__ xT) {
  __shared__ float tile[32 * 33];
  int blk = blockIdx.x;            // b*256 + ct*32 + h  (4096 blocks)
  int h  = blk & 31;
  int ct = (blk >> 5) & 7;
  int b  = blk >> 8;
  int tid = threadIdx.x;
  {
    int w = tid & 31, c0 = tid >> 5;
#pragma unroll
    for (int i = 0; i < 4; ++i) {
      int ci = c0 + 8 * i;
      tile[w * 33 + ci] = x[((b * 256 + ct * 32 + ci) * 32 + h) * 32 + w];
    }
  }
  __syncthreads();
  {
    int ci = tid & 31, w0 = tid >> 5;
#pragma unroll
    for (int i = 0; i < 4; ++i) {
      int w = w0 + 8 * i;
      xT[((b * 34 + (h + 1)) * 34 + (w + 1)) * 256 + ct * 32 + ci] =
          __float2bfloat16(tile[w * 33 + ci]);
    }
  }
}

// ---------------------------------------------------------------------------
// Kernel 1: build dense M_s = B2_s * B1_s (exact f32 in LDS), write W = M/9 as
// bf16 in the GEMM A-staging order. Block = (s, 64-column group); 36 blocks.
// Block 36 reduces bias: biasout[n] = (1/9) sum_s bias[s][n].
// ---------------------------------------------------------------------------
__global__ __launch_bounds__(256) void k_build_w(const float* __restrict__ tw1,
                                                 const float* __restrict__ tw2,
                                                 const float* __restrict__ bias,
                                                 __hip_bfloat16* __restrict__ Wg,
                                                 float* __restrict__ biasout) {
  __shared__ float mat[256 * 64];  // [row n][col c], col-contiguous
  int blk = blockIdx.x;
  int tid = threadIdx.x;
  if (blk == 36) {
    if (tid < 256) {
      float a = 0.f;
#pragma unroll
      for (int s = 0; s < 9; ++s) a += bias[s * 256 + tid];
      biasout[tid] = a * (1.f / 9.f);
    }
    return;
  }
  int sidx = blk >> 2;
  int colbase = (blk & 3) * 64;

  for (int idx = tid; idx < 256 * 64; idx += 256) {
    int r = idx >> 6, c = idx & 63;
    mat[idx] = (r == colbase + c) ? 1.f : 0.f;
  }

  int c = tid & 63, qb = tid >> 6;
  // Phase 0: twiddle1, strides 128..1 (increasing=False). Phase 1: twiddle2, 1..128.
  for (int ph = 0; ph < 2; ++ph) {
    const float* tw = ph ? tw2 : tw1;
    for (int si = 0; si < 8; ++si) {
      int lg = ph ? si : (7 - si);
      int st = 1 << lg;
      __syncthreads();
      for (int i = 0; i < 32; ++i) {
        int q = qb * 32 + i;             // pair id 0..127, wave-uniform
        int li = q & (st - 1);
        int gi = q >> lg;
        int p0 = (gi << (lg + 1)) | li;
        int p1 = p0 + st;
        const float* t4 = tw + (sidx * 255 + st - 1 + li) * 4;  // [i][k]
        float t00 = t4[0], t01 = t4[1], t10 = t4[2], t11 = t4[3];
        float x0 = mat[p0 * 64 + c], x1 = mat[p1 * 64 + c];
        mat[p0 * 64 + c] = t00 * x0 + t01 * x1;
        mat[p1 * 64 + c] = t10 * x0 + t11 * x1;
      }
    }
  }
  __syncthreads();

  for (int idx = tid; idx < 256 * 64; idx += 256) {
    int r = idx >> 6, cc = idx & 63;
    int cg = colbase + cc;
    int chunk = cg >> 5, quad = (cg >> 3) & 3, c8 = cg & 7;
    int nt = r >> 7, nl = r & 127;
    int o = ((((sidx * 8 + chunk) * 2 + nt) * 4 + quad) * 128 + nl) * 8 + c8;
    Wg[o] = __float2bfloat16(mat[idx] * (1.f / 9.f));
  }
}

// ---------------------------------------------------------------------------
// Kernel 2: implicit-GEMM conv.  out[n,p] = sum_{s,c} W_s[n,c] * xT[p shifted by s][c]
// M=256 (2 n-tiles of 128), N=16384 (128 pixel tiles: 4 rows x 32 cols), K=9*256.
// 256 blocks x 256 threads (4 waves, 2x2), mfma 16x16x32 bf16, acc 4x4/wave.
// A LDS: [quad][n128][8c] (8 KB, staged contiguously via global_load_lds x16).
// B LDS: [quad][pos204][8c] (13 KB halo = 6 rows x 34 cols x 32 ch), staged once
// per c-chunk, reused across all 9 offsets. Both double-buffered; prefetch for
// step t+1 is issued before compute(t) so the barrier vmcnt drain is hidden.
// ---------------------------------------------------------------------------
#define LDS_A_SZ 8192
#define LDS_B_SZ (816 * 16)

__global__ __launch_bounds__(256) void k_gemm(const __hip_bfloat16* __restrict__ xT,
                                              const __hip_bfloat16* __restrict__ Wg,
                                              const float* __restrict__ biasout,
                                              float* __restrict__ out) {
  __shared__ __align__(16) char lds[2 * LDS_A_SZ + 2 * LDS_B_SZ];
  const char* WgB = (const char*)Wg;
  const char* xTB = (const char*)xT;

  int blk = blockIdx.x;
  int nt = blk & 1;
  int pt = blk >> 1;
  int b  = pt >> 3;
  int h0 = (pt & 7) * 4;  // tile covers unpadded rows h0..h0+3 -> padded rows h0..h0+5

  int tid  = threadIdx.x;
  int lane = tid & 63;
  int wave = tid >> 6;
  int wm = wave >> 1, wn = wave & 1;
  int q = lane >> 4, l16 = lane & 15;

  float4v acc[4][4];
#pragma unroll
  for (int r = 0; r < 4; ++r)
#pragma unroll
    for (int j = 0; j < 4; ++j) acc[r][j] = (float4v){0.f, 0.f, 0.f, 0.f};

  auto stage_a = [&](int step, int buf) {
    int chunk = step / 9, s = step - chunk * 9;
    int off = ((s * 8 + chunk) * 2 + nt) * 8192;
#pragma unroll
    for (int r = 0; r < 2; ++r) {
      int slotbase = r * 256 + wave * 64;  // wave-uniform
      const char* g = WgB + off + (slotbase + lane) * 16;
      char* l = lds + buf * LDS_A_SZ + slotbase * 16;
      __builtin_amdgcn_global_load_lds((const __attribute__((address_space(1))) void*)g,
                                       (__attribute__((address_space(3))) void*)l,
                                       16, 0, 0);
    }
  };

  auto stage_b = [&](int chunk, int buf) {
#pragma unroll
    for (int r = 0; r < 4; ++r) {
      int slot = r * 256 + tid;  // 816 slots = [quad][pos]
      if (slot < 816) {
        int quad = slot / 204;
        int pos  = slot - quad * 204;
        int hhrel = pos / 34;
        int ww = pos - hhrel * 34;
        const char* g = xTB + (((b * 34 + h0 + hhrel) * 34 + ww) * 256 +
                               chunk * 32 + quad * 8) * 2;
        char* l = lds + 2 * LDS_A_SZ + buf * LDS_B_SZ + (r * 256 + wave * 64) * 16;
        __builtin_amdgcn_global_load_lds((const __attribute__((address_space(1))) void*)g,
                                         (__attribute__((address_space(3))) void*)l,
                                         16, 0, 0);
      }
    }
  };

  auto do_step = [&](int step) {
    int chunk = step / 9, s = step - chunk * 9;
    int si = s / 3, sj = s - si * 3;
    const char* Ab = lds + (step & 1) * LDS_A_SZ;
    const char* Bb = lds + 2 * LDS_A_SZ + (chunk & 1) * LDS_B_SZ;
    short8 af[4], bfr[4];
#pragma unroll
    for (int r = 0; r < 4; ++r) {
      int nl = wm * 64 + r * 16 + l16;
      af[r] = *(const short8*)(Ab + (q * 128 + nl) * 16);   // A[m=l16-ish][k=q*8+j]
    }
#pragma unroll
    for (int j = 0; j < 4; ++j) {
      int p = wn * 64 + j * 16 + l16;
      int pos = ((p >> 5) + si) * 34 + (p & 31) + sj;
      bfr[j] = *(const short8*)(Bb + (q * 204 + pos) * 16); // B[k=q*8+j][n=pixel]
    }
#pragma unroll
    for (int r = 0; r < 4; ++r)
#pragma unroll
      for (int j = 0; j < 4; ++j)
        acc[r][j] = __builtin_amdgcn_mfma_f32_16x16x32_bf16(af[r], bfr[j], acc[r][j], 0, 0, 0);
  };

  stage_a(0, 0);
  stage_b(0, 0);
  __syncthreads();
  for (int step = 0; step < 72; ++step) {
    int nxt = step + 1;
    if (nxt < 72) {
      stage_a(nxt, nxt & 1);                      // prefetch into the idle A buffer
      if (nxt % 9 == 0) stage_b(nxt / 9, (nxt / 9) & 1);  // next c-chunk halo
    }
    do_step(step);
    __syncthreads();  // vmcnt drain covers the prefetch; hidden behind 64 MFMAs
  }

  // Epilogue: D row=(q*4+reg), col=l16 (m89-verified C/D layout). out is f32 NCHW.
  int nbase = nt * 128 + wm * 64;
#pragma unroll
  for (int j = 0; j < 4; ++j) {
    int p = wn * 64 + j * 16 + l16;
    int hr = h0 + (p >> 5), wc = p & 31;
#pragma unroll
    for (int r = 0; r < 4; ++r) {
      float4v v = acc[r][j];
#pragma unroll
      for (int reg = 0; reg < 4; ++reg) {
        int n = nbase + r * 16 + q * 4 + reg;
        out[((b * 256 + n) * 32 + hr) * 32 + wc] = v[reg] + biasout[n];
      }
    }
  }
}

// ---------------------------------------------------------------------------
extern "C" void kernel_launch(void* const* d_in, const int* in_sizes, int n_in,
                              void* d_out, int out_size, void* d_ws, size_t ws_size,
                              hipStream_t stream) {
  const float* x    = (const float*)d_in[0];
  const float* tw1  = (const float*)d_in[1];
  const float* tw2  = (const float*)d_in[2];
  const float* bias = (const float*)d_in[3];
  float* out = (float*)d_out;

  char* ws = (char*)d_ws;
  __hip_bfloat16* xT = (__hip_bfloat16*)ws;
  __hip_bfloat16* Wg = (__hip_bfloat16*)(ws + XT_BYTES);
  float* biasout     = (float*)(ws + XT_BYTES + WG_BYTES);

  hipMemsetAsync(xT, 0, XT_BYTES, stream);               // zero pad ring
  k_transpose<<<4096, 256, 0, stream>>>(x, xT);
  k_build_w<<<37, 256, 0, stream>>>(tw1, tw2, bias, Wg, biasout);
  k_gemm<<<256, 256, 0, stream>>>(xT, Wg, biasout, out);
}

// Round 2
// 129.676 us; speedup vs baseline: 1.2509x; 1.2509x over previous
//
#include <hip/hip_runtime.h>
#include <hip/hip_bf16.h>

typedef __attribute__((ext_vector_type(8))) short short8;
typedef __attribute__((ext_vector_type(4))) float float4v;

// Workspace layout (bytes):
//   xT   bf16 [16][34][34][256]                      : 9,469,952
//   Wg   bf16 [9][8][2][4][128][8]  (s,chunk,nt,quad,n,c8) : 1,179,648
//   biasout f32 [256]                                : 1,024
#define XT_ELEMS (16*34*34*256)
#define WG_ELEMS (9*8*2*4*128*8)
#define XT_BYTES (XT_ELEMS*2)
#define WG_BYTES (WG_ELEMS*2)

// ---------------------------------------------------------------------------
// Kernel 0: x f32 [16][256][32][32] -> xT bf16 [16][34][34][256] (interior).
// Pad ring is zeroed by hipMemsetAsync before this kernel.
// ---------------------------------------------------------------------------
__global__ __launch_bounds__(256) void k_transpose(const float* __restrict__ x,
                                                   __hip_bfloat16* __restrict__ xT) {
  __shared__ float tile[32 * 33];
  int blk = blockIdx.x;            // b*256 + ct*32 + h  (4096 blocks)
  int h  = blk & 31;
  int ct = (blk >> 5) & 7;
  int b  = blk >> 8;
  int tid = threadIdx.x;
  {
    int w = tid & 31, c0 = tid >> 5;
#pragma unroll
    for (int i = 0; i < 4; ++i) {
      int ci = c0 + 8 * i;
      tile[w * 33 + ci] = x[((b * 256 + ct * 32 + ci) * 32 + h) * 32 + w];
    }
  }
  __syncthreads();
  {
    int ci = tid & 31, w0 = tid >> 5;
#pragma unroll
    for (int i = 0; i < 4; ++i) {
      int w = w0 + 8 * i;
      xT[((b * 34 + (h + 1)) * 34 + (w + 1)) * 256 + ct * 32 + ci] =
          __float2bfloat16(tile[w * 33 + ci]);
    }
  }
}

// ---------------------------------------------------------------------------
// Kernel 1 (R1 rewrite): build dense M_s = B2_s * B1_s, exact f32 in LDS.
// Block = (s, 16-column group) -> 144 blocks + 1 bias block.
// Per stage: read phase (all mat+twiddle LDS reads pipeline into registers,
// one lgkmcnt wait) then write phase — no serial RMW chain, no in-loop global
// loads (twiddles pre-staged to LDS once). mat stride 17 breaks bank aliasing.
// ---------------------------------------------------------------------------
__global__ __launch_bounds__(256) void k_build_w(const float* __restrict__ tw1,
                                                 const float* __restrict__ tw2,
                                                 const float* __restrict__ bias,
                                                 __hip_bfloat16* __restrict__ Wg,
                                                 float* __restrict__ biasout) {
  __shared__ float mat[256 * 17];                 // [row][col], +1 pad
  __shared__ __align__(16) float tws[2 * 255 * 4];
  int blk = blockIdx.x;
  int tid = threadIdx.x;
  if (blk == 144) {
    if (tid < 256) {
      float a = 0.f;
#pragma unroll
      for (int s = 0; s < 9; ++s) a += bias[s * 256 + tid];
      biasout[tid] = a * (1.f / 9.f);
    }
    return;
  }
  int sidx = blk >> 4;            // 0..8
  int colbase = (blk & 15) * 16;  // 0..240

  // Stage all twiddles for this s into LDS (2 x 255 x 4 floats).
  for (int i = tid; i < 255 * 4; i += 256) {
    tws[i]           = tw1[sidx * 255 * 4 + i];
    tws[255 * 4 + i] = tw2[sidx * 255 * 4 + i];
  }
  // Identity columns colbase..colbase+15.
  {
    int r = tid;
#pragma unroll
    for (int c = 0; c < 16; ++c) mat[r * 17 + c] = (r == colbase + c) ? 1.f : 0.f;
  }

  int c  = tid & 15;
  int pg = tid >> 4;  // pair-group 0..15, pairs q = pg*8 + i
  // Phase 0: twiddle1, strides 128..1 (increasing=False). Phase 1: twiddle2, 1..128.
  for (int ph = 0; ph < 2; ++ph) {
    for (int si = 0; si < 8; ++si) {
      int lg = ph ? si : (7 - si);
      int st = 1 << lg;
      __syncthreads();
      float x0[8], x1[8], t0[8], t1[8], t2[8], t3[8];
#pragma unroll
      for (int i = 0; i < 8; ++i) {
        int q  = pg * 8 + i;
        int li = q & (st - 1);
        int gi = q >> lg;
        int p0 = (gi << (lg + 1)) | li;
        int p1 = p0 + st;
        const float4* t4 = (const float4*)&tws[(ph * 255 + st - 1 + li) * 4];
        float4 tv = *t4;
        t0[i] = tv.x; t1[i] = tv.y; t2[i] = tv.z; t3[i] = tv.w;
        x0[i] = mat[p0 * 17 + c];
        x1[i] = mat[p1 * 17 + c];
      }
#pragma unroll
      for (int i = 0; i < 8; ++i) {
        int q  = pg * 8 + i;
        int li = q & (st - 1);
        int gi = q >> lg;
        int p0 = (gi << (lg + 1)) | li;
        int p1 = p0 + st;
        mat[p0 * 17 + c] = t0[i] * x0[i] + t1[i] * x1[i];
        mat[p1 * 17 + c] = t2[i] * x0[i] + t3[i] * x1[i];
      }
    }
  }
  __syncthreads();

  // Write out in GEMM A-staging order, fold 1/9.
  for (int idx = tid; idx < 256 * 16; idx += 256) {
    int r = idx >> 4, cc = idx & 15;
    int cg = colbase + cc;
    int chunk = cg >> 5, quad = (cg >> 3) & 3, c8 = cg & 7;
    int nt = r >> 7, nl = r & 127;
    int o = ((((sidx * 8 + chunk) * 2 + nt) * 4 + quad) * 128 + nl) * 8 + c8;
    Wg[o] = __float2bfloat16(mat[r * 17 + cc] * (1.f / 9.f));
  }
}

// ---------------------------------------------------------------------------
// Kernel 2: implicit-GEMM conv.  out[n,p] = sum_{s,c} W_s[n,c] * xT[p shifted by s][c]
// M=256 (2 n-tiles of 128), N=16384 (128 pixel tiles: 4 rows x 32 cols), K=9*256.
// 256 blocks x 256 threads (4 waves, 2x2), mfma 16x16x32 bf16, acc 4x4/wave.
// ---------------------------------------------------------------------------
#define LDS_A_SZ 8192
#define LDS_B_SZ (816 * 16)

__global__ __launch_bounds__(256) void k_gemm(const __hip_bfloat16* __restrict__ xT,
                                              const __hip_bfloat16* __restrict__ Wg,
                                              const float* __restrict__ biasout,
                                              float* __restrict__ out) {
  __shared__ __align__(16) char lds[2 * LDS_A_SZ + 2 * LDS_B_SZ];
  const char* WgB = (const char*)Wg;
  const char* xTB = (const char*)xT;

  int blk = blockIdx.x;
  int nt = blk & 1;
  int pt = blk >> 1;
  int b  = pt >> 3;
  int h0 = (pt & 7) * 4;  // tile covers unpadded rows h0..h0+3 -> padded rows h0..h0+5

  int tid  = threadIdx.x;
  int lane = tid & 63;
  int wave = tid >> 6;
  int wm = wave >> 1, wn = wave & 1;
  int q = lane >> 4, l16 = lane & 15;

  float4v acc[4][4];
#pragma unroll
  for (int r = 0; r < 4; ++r)
#pragma unroll
    for (int j = 0; j < 4; ++j) acc[r][j] = (float4v){0.f, 0.f, 0.f, 0.f};

  auto stage_a = [&](int step, int buf) {
    int chunk = step / 9, s = step - chunk * 9;
    int off = ((s * 8 + chunk) * 2 + nt) * 8192;
#pragma unroll
    for (int r = 0; r < 2; ++r) {
      int slotbase = r * 256 + wave * 64;  // wave-uniform
      const char* g = WgB + off + (slotbase + lane) * 16;
      char* l = lds + buf * LDS_A_SZ + slotbase * 16;
      __builtin_amdgcn_global_load_lds((const __attribute__((address_space(1))) void*)g,
                                       (__attribute__((address_space(3))) void*)l,
                                       16, 0, 0);
    }
  };

  auto stage_b = [&](int chunk, int buf) {
#pragma unroll
    for (int r = 0; r < 4; ++r) {
      int slot = r * 256 + tid;  // 816 slots = [quad][pos]
      if (slot < 816) {
        int quad = slot / 204;
        int pos  = slot - quad * 204;
        int hhrel = pos / 34;
        int ww = pos - hhrel * 34;
        const char* g = xTB + (((b * 34 + h0 + hhrel) * 34 + ww) * 256 +
                               chunk * 32 + quad * 8) * 2;
        char* l = lds + 2 * LDS_A_SZ + buf * LDS_B_SZ + (r * 256 + wave * 64) * 16;
        __builtin_amdgcn_global_load_lds((const __attribute__((address_space(1))) void*)g,
                                         (__attribute__((address_space(3))) void*)l,
                                         16, 0, 0);
      }
    }
  };

  auto do_step = [&](int step) {
    int chunk = step / 9, s = step - chunk * 9;
    int si = s / 3, sj = s - si * 3;
    const char* Ab = lds + (step & 1) * LDS_A_SZ;
    const char* Bb = lds + 2 * LDS_A_SZ + (chunk & 1) * LDS_B_SZ;
    short8 af[4], bfr[4];
#pragma unroll
    for (int r = 0; r < 4; ++r) {
      int nl = wm * 64 + r * 16 + l16;
      af[r] = *(const short8*)(Ab + (q * 128 + nl) * 16);   // A[m][k=q*8+j]
    }
#pragma unroll
    for (int j = 0; j < 4; ++j) {
      int p = wn * 64 + j * 16 + l16;
      int pos = ((p >> 5) + si) * 34 + (p & 31) + sj;
      bfr[j] = *(const short8*)(Bb + (q * 204 + pos) * 16); // B[k=q*8+j][n=pixel]
    }
#pragma unroll
    for (int r = 0; r < 4; ++r)
#pragma unroll
      for (int j = 0; j < 4; ++j)
        acc[r][j] = __builtin_amdgcn_mfma_f32_16x16x32_bf16(af[r], bfr[j], acc[r][j], 0, 0, 0);
  };

  stage_a(0, 0);
  stage_b(0, 0);
  __syncthreads();
  for (int step = 0; step < 72; ++step) {
    int nxt = step + 1;
    if (nxt < 72) {
      stage_a(nxt, nxt & 1);                      // prefetch into the idle A buffer
      if (nxt % 9 == 0) stage_b(nxt / 9, (nxt / 9) & 1);  // next c-chunk halo
    }
    do_step(step);
    __syncthreads();  // vmcnt drain covers the prefetch; hidden behind 64 MFMAs
  }

  // Epilogue: D row=(q*4+reg), col=l16 (m89-verified C/D layout). out is f32 NCHW.
  int nbase = nt * 128 + wm * 64;
#pragma unroll
  for (int j = 0; j < 4; ++j) {
    int p = wn * 64 + j * 16 + l16;
    int hr = h0 + (p >> 5), wc = p & 31;
#pragma unroll
    for (int r = 0; r < 4; ++r) {
      float4v v = acc[r][j];
#pragma unroll
      for (int reg = 0; reg < 4; ++reg) {
        int n = nbase + r * 16 + q * 4 + reg;
        out[((b * 256 + n) * 32 + hr) * 32 + wc] = v[reg] + biasout[n];
      }
    }
  }
}

// ---------------------------------------------------------------------------
extern "C" void kernel_launch(void* const* d_in, const int* in_sizes, int n_in,
                              void* d_out, int out_size, void* d_ws, size_t ws_size,
                              hipStream_t stream) {
  const float* x    = (const float*)d_in[0];
  const float* tw1  = (const float*)d_in[1];
  const float* tw2  = (const float*)d_in[2];
  const float* bias = (const float*)d_in[3];
  float* out = (float*)d_out;

  char* ws = (char*)d_ws;
  __hip_bfloat16* xT = (__hip_bfloat16*)ws;
  __hip_bfloat16* Wg = (__hip_bfloat16*)(ws + XT_BYTES);
  float* biasout     = (float*)(ws + XT_BYTES + WG_BYTES);

  hipMemsetAsync(xT, 0, XT_BYTES, stream);               // zero pad ring
  k_transpose<<<4096, 256, 0, stream>>>(x, xT);
  k_build_w<<<145, 256, 0, stream>>>(tw1, tw2, bias, Wg, biasout);
  k_gemm<<<256, 256, 0, stream>>>(xT, Wg, biasout, out);
}

// Round 3
// 127.102 us; speedup vs baseline: 1.2762x; 1.0203x over previous
//
#include <hip/hip_runtime.h>
#include <hip/hip_bf16.h>

typedef __attribute__((ext_vector_type(8))) short short8;
typedef __attribute__((ext_vector_type(4))) float float4v;

// Workspace layout (bytes):
//   xT   bf16 [16][34][34][256]                          : 9,469,952
//   Wg   bf16 [9][4][2][8][128][8] (s,pair,nt,qq,n,c8)   : 1,179,648
//   biasout f32 [256]                                    : 1,024
#define XT_ELEMS (16*34*34*256)
#define WG_ELEMS (9*4*2*8*128*8)
#define XT_BYTES (XT_ELEMS*2)
#define WG_BYTES (WG_ELEMS*2)

// ---------------------------------------------------------------------------
// Kernel 0 (R2 rewrite): x f32 [16][256][32][32] -> xT bf16 [16][34][34][256].
// 512 blocks = (b, h), 2 blocks/CU. float4 global reads, LDS 256x33 f32 tile,
// packed bf16x2 writes (256 c contiguous per w => full-width segments).
// Blocks with h<2 also zero the pad ring (replaces the old memset dispatch).
// ---------------------------------------------------------------------------
__global__ __launch_bounds__(256) void k_transpose(const float* __restrict__ x,
                                                   __hip_bfloat16* __restrict__ xT) {
  __shared__ float tile[256 * 33];
  int blk = blockIdx.x;            // b*32 + h
  int h = blk & 31, b = blk >> 5;
  int tid = threadIdx.x;
  {
    int w4 = (tid & 7) * 4, c0 = tid >> 3;   // 8 lanes cover one c-row (128 B)
#pragma unroll
    for (int j = 0; j < 8; ++j) {
      int ci = c0 + 32 * j;
      float4 v = *(const float4*)&x[((b * 256 + ci) * 32 + h) * 32 + w4];
      *(float4*)&tile[ci * 33 + w4] = v;
    }
  }
  __syncthreads();
  {
    int c2 = (tid & 127) * 2, wbase = (tid >> 7) * 16;
#pragma unroll
    for (int i = 0; i < 16; ++i) {
      int w = wbase + i;
      __hip_bfloat162 pk;
      pk.x = __float2bfloat16(tile[c2 * 33 + w]);
      pk.y = __float2bfloat16(tile[(c2 + 1) * 33 + w]);
      *(__hip_bfloat162*)&xT[((b * 34 + h + 1) * 34 + (w + 1)) * 256 + c2] = pk;
    }
  }
  if (h < 2) {   // zero pad ring: h==0 -> row 0 + col 0; h==1 -> row 33 + col 33
    uint4 z4 = {0u, 0u, 0u, 0u};
    int edge = h * 33;
    uint4* rowp = (uint4*)&xT[((b * 34 + edge) * 34) * 256];
    for (int i = tid; i < 1088; i += 256) rowp[i] = z4;     // 34*256 bf16
    for (int i = tid; i < 1024; i += 256) {                 // 32 rows x 256 c
      int hh = 1 + (i >> 5);
      int c16 = (i & 31) * 8;
      *(uint4*)&xT[((b * 34 + hh) * 34 + edge) * 256 + c16] = z4;
    }
  }
}

// ---------------------------------------------------------------------------
// Kernel 1: build dense M_s = B2_s * B1_s, exact f32 in LDS.
// Block = (s, 16-column group) -> 144 blocks + 1 bias block.
// ---------------------------------------------------------------------------
__global__ __launch_bounds__(256) void k_build_w(const float* __restrict__ tw1,
                                                 const float* __restrict__ tw2,
                                                 const float* __restrict__ bias,
                                                 __hip_bfloat16* __restrict__ Wg,
                                                 float* __restrict__ biasout) {
  __shared__ float mat[256 * 17];
  __shared__ __align__(16) float tws[2 * 255 * 4];
  int blk = blockIdx.x;
  int tid = threadIdx.x;
  if (blk == 144) {
    if (tid < 256) {
      float a = 0.f;
#pragma unroll
      for (int s = 0; s < 9; ++s) a += bias[s * 256 + tid];
      biasout[tid] = a * (1.f / 9.f);
    }
    return;
  }
  int sidx = blk >> 4;
  int colbase = (blk & 15) * 16;

  for (int i = tid; i < 255 * 4; i += 256) {
    tws[i]           = tw1[sidx * 255 * 4 + i];
    tws[255 * 4 + i] = tw2[sidx * 255 * 4 + i];
  }
  {
    int r = tid;
#pragma unroll
    for (int c = 0; c < 16; ++c) mat[r * 17 + c] = (r == colbase + c) ? 1.f : 0.f;
  }

  int c  = tid & 15;
  int pg = tid >> 4;
  for (int ph = 0; ph < 2; ++ph) {
    for (int si = 0; si < 8; ++si) {
      int lg = ph ? si : (7 - si);
      int st = 1 << lg;
      __syncthreads();
      float x0[8], x1[8], t0[8], t1[8], t2[8], t3[8];
#pragma unroll
      for (int i = 0; i < 8; ++i) {
        int qp = pg * 8 + i;
        int li = qp & (st - 1);
        int gi = qp >> lg;
        int p0 = (gi << (lg + 1)) | li;
        int p1 = p0 + st;
        float4 tv = *(const float4*)&tws[(ph * 255 + st - 1 + li) * 4];
        t0[i] = tv.x; t1[i] = tv.y; t2[i] = tv.z; t3[i] = tv.w;
        x0[i] = mat[p0 * 17 + c];
        x1[i] = mat[p1 * 17 + c];
      }
#pragma unroll
      for (int i = 0; i < 8; ++i) {
        int qp = pg * 8 + i;
        int li = qp & (st - 1);
        int gi = qp >> lg;
        int p0 = (gi << (lg + 1)) | li;
        int p1 = p0 + st;
        mat[p0 * 17 + c] = t0[i] * x0[i] + t1[i] * x1[i];
        mat[p1 * 17 + c] = t2[i] * x0[i] + t3[i] * x1[i];
      }
    }
  }
  __syncthreads();

  // Scatter in GEMM A-staging order: [s][pair][nt][qq][nl][c8], fold 1/9.
  for (int idx = tid; idx < 256 * 16; idx += 256) {
    int r = idx >> 4, cc = idx & 15;
    int cg = colbase + cc;
    int pr = cg >> 6, qq = (cg >> 3) & 7, c8 = cg & 7;
    int nt = r >> 7, nl = r & 127;
    int o = ((((sidx * 4 + pr) * 2 + nt) * 8 + qq) * 128 + nl) * 8 + c8;
    Wg[o] = __float2bfloat16(mat[r * 17 + cc] * (1.f / 9.f));
  }
}

// ---------------------------------------------------------------------------
// Kernel 2 (R2 restructure): implicit-GEMM conv, K=64 per step.
// M=256 (2 nt of 128), N=16384 (128 ptiles: 4 rows x 32 cols), K=9*256.
// 36 steps = 4 channel-pairs x 9 offsets; 32 MFMA/step.
// A: 16 KB/step, double-buffered, contiguous global_load_lds x16.
// B: 26 KB halo per channel-pair (8 qq x 204 pos x 16 B), single-buffered,
//    staged at pair boundaries (4x), reused across 9 offsets.
// LDS total 57.5 KB. Drains: 36 (A in flight during 32 MFMAs) + 3 (B).
// ---------------------------------------------------------------------------
#define LDS_A_SZ 16384
#define LDS_B_SZ (8 * 204 * 16)

__global__ __launch_bounds__(256) void k_gemm(const __hip_bfloat16* __restrict__ xT,
                                              const __hip_bfloat16* __restrict__ Wg,
                                              const float* __restrict__ biasout,
                                              float* __restrict__ out) {
  __shared__ __align__(16) char lds[2 * LDS_A_SZ + LDS_B_SZ];
  const char* WgB = (const char*)Wg;
  const char* xTB = (const char*)xT;

  int blk = blockIdx.x;
  int nt = blk & 1;
  int pt = blk >> 1;
  int b  = pt >> 3;
  int h0 = (pt & 7) * 4;

  int tid  = threadIdx.x;
  int lane = tid & 63;
  int wave = tid >> 6;
  int wm = wave >> 1, wn = wave & 1;
  int q = lane >> 4, l16 = lane & 15;

  float4v acc[4][4];
#pragma unroll
  for (int r = 0; r < 4; ++r)
#pragma unroll
    for (int j = 0; j < 4; ++j) acc[r][j] = (float4v){0.f, 0.f, 0.f, 0.f};

  auto stage_a = [&](int step, int buf) {
    int p = step / 9, s = step - p * 9;
    const char* g = WgB + (((s * 4 + p) * 2 + nt) * 16384);
#pragma unroll
    for (int i = 0; i < 4; ++i) {
      int slotbase = i * 256 + wave * 64;   // wave-uniform
      __builtin_amdgcn_global_load_lds(
          (const __attribute__((address_space(1))) void*)(g + (slotbase + lane) * 16),
          (__attribute__((address_space(3))) void*)(lds + buf * LDS_A_SZ + slotbase * 16),
          16, 0, 0);
    }
  };

  auto stage_b = [&](int p) {
#pragma unroll
    for (int i = 0; i < 7; ++i) {
      int slot = i * 256 + tid;             // 1632 slots = [qq][pos]
      if (slot < 1632) {
        int qq  = slot / 204;
        int pos = slot - qq * 204;
        int hh  = pos / 34;
        int ww  = pos - hh * 34;
        const char* g = xTB + (((b * 34 + h0 + hh) * 34 + ww) * 256 +
                               p * 64 + qq * 8) * 2;
        __builtin_amdgcn_global_load_lds(
            (const __attribute__((address_space(1))) void*)g,
            (__attribute__((address_space(3))) void*)(lds + 2 * LDS_A_SZ +
                                                     (i * 256 + wave * 64) * 16),
            16, 0, 0);
      }
    }
  };

  auto do_step = [&](int step) {
    int p = step / 9, s = step - p * 9;
    int si = s / 3, sj = s - si * 3;
    const char* Ab = lds + (step & 1) * LDS_A_SZ;
    const char* Bb = lds + 2 * LDS_A_SZ;
    short8 af[8], bfr[8];
#pragma unroll
    for (int r = 0; r < 4; ++r) {
      int nl = wm * 64 + r * 16 + l16;
      af[r]     = *(const short8*)(Ab + (q * 128 + nl) * 16);
      af[r + 4] = *(const short8*)(Ab + ((q + 4) * 128 + nl) * 16);
    }
#pragma unroll
    for (int j = 0; j < 4; ++j) {
      int pp = wn * 64 + j * 16 + l16;
      int pos = ((pp >> 5) + si) * 34 + (pp & 31) + sj;
      bfr[j]     = *(const short8*)(Bb + (q * 204 + pos) * 16);
      bfr[j + 4] = *(const short8*)(Bb + ((q + 4) * 204 + pos) * 16);
    }
#pragma unroll
    for (int r = 0; r < 4; ++r)
#pragma unroll
      for (int j = 0; j < 4; ++j) {
        acc[r][j] = __builtin_amdgcn_mfma_f32_16x16x32_bf16(af[r], bfr[j], acc[r][j], 0, 0, 0);
        acc[r][j] = __builtin_amdgcn_mfma_f32_16x16x32_bf16(af[r + 4], bfr[j + 4], acc[r][j], 0, 0, 0);
      }
  };

  stage_a(0, 0);
  stage_b(0);
  __syncthreads();
  for (int step = 0; step < 36; ++step) {
    int p = step / 9, s = step - p * 9;
    if (s == 8) {
      if (p < 3) stage_a(step + 1, (step + 1) & 1);  // next pair's first A slab
      do_step(step);
      __syncthreads();
      if (p < 3) { stage_b(p + 1); __syncthreads(); }  // B single-buffer swap
    } else {
      stage_a(step + 1, (step + 1) & 1);
      do_step(step);
      __syncthreads();
    }
  }

  // Epilogue: D row=(q*4+reg), col=l16 (m89-verified C/D layout). out f32 NCHW.
  int nbase = nt * 128 + wm * 64;
#pragma unroll
  for (int j = 0; j < 4; ++j) {
    int pp = wn * 64 + j * 16 + l16;
    int hr = h0 + (pp >> 5), wc = pp & 31;
#pragma unroll
    for (int r = 0; r < 4; ++r) {
      float4v v = acc[r][j];
#pragma unroll
      for (int reg = 0; reg < 4; ++reg) {
        int n = nbase + r * 16 + q * 4 + reg;
        out[((b * 256 + n) * 32 + hr) * 32 + wc] = v[reg] + biasout[n];
      }
    }
  }
}

// ---------------------------------------------------------------------------
extern "C" void kernel_launch(void* const* d_in, const int* in_sizes, int n_in,
                              void* d_out, int out_size, void* d_ws, size_t ws_size,
                              hipStream_t stream) {
  const float* x    = (const float*)d_in[0];
  const float* tw1  = (const float*)d_in[1];
  const float* tw2  = (const float*)d_in[2];
  const float* bias = (const float*)d_in[3];
  float* out = (float*)d_out;

  char* ws = (char*)d_ws;
  __hip_bfloat16* xT = (__hip_bfloat16*)ws;
  __hip_bfloat16* Wg = (__hip_bfloat16*)(ws + XT_BYTES);
  float* biasout     = (float*)(ws + XT_BYTES + WG_BYTES);

  k_transpose<<<512, 256, 0, stream>>>(x, xT);
  k_build_w<<<145, 256, 0, stream>>>(tw1, tw2, bias, Wg, biasout);
  k_gemm<<<256, 256, 0, stream>>>(xT, Wg, biasout, out);
}